// Round 1
// baseline (1478.870 us; speedup 1.0000x reference)
//
#include <hip/hip_runtime.h>

// ---------------- problem constants ----------------
#define T_TOK 8192      // B*S tokens
#define D_DIM 1024
#define F_DIM 4096
#define E_EXP 8
#define DT_DIM 256
#define PPAD 17408      // 16384 pairs + up to 8*127 padding, rounded

// ---------------- workspace layout (bytes) ----------------
#define A_XB   0u                    // bf16 X   [8192][1024]   16,777,216
#define A_WT   16777216u             // bf16 W1T then W2T       67,108,864
#define A_H    83886080u             // bf16 h   [17408][4096] 142,606,336
#define A_Y    226492416u            // bf16 Y   [17408][1024]  35,651,584
#define A_META 262144000u
// meta byte offsets
#define MO_COUNTS 0
#define MO_FILL   64
#define MO_PB     128
#define MO_NT     192
#define MO_SPROB  256
#define MO_TILEE  512
#define MO_TILERB 1280
#define MO_ROUTEE 2048      // int[16384]
#define MO_ROUTEW 67584     // f32[16384]
#define MO_TSLOT  133120    // int[16384]
#define MO_PTOK   198656    // int[17408]
#define META_BYTES 268288
#define META_INTS  (META_BYTES/4)

using bf16x8 = __attribute__((ext_vector_type(8))) short;
using f32x4  = __attribute__((ext_vector_type(4))) float;
typedef unsigned short u16;

__device__ __forceinline__ u16 f2bf(float f) {
  union { float f; unsigned u; } v; v.f = f;
  unsigned r = v.u + 0x7FFFu + ((v.u >> 16) & 1u);   // RNE
  return (u16)(r >> 16);
}
__device__ __forceinline__ float bf2f(u16 h) {
  union { unsigned u; float f; } v; v.u = ((unsigned)h) << 16; return v.f;
}
__device__ __forceinline__ void gload16(const void* gsrc, void* ldst) {
  __builtin_amdgcn_global_load_lds(
      (const __attribute__((address_space(1))) void*)gsrc,
      (__attribute__((address_space(3))) void*)ldst, 16, 0, 0);
}

// ---------------- zero meta ----------------
__global__ void zerok(int* p, int n) {
  int i = blockIdx.x * 256 + threadIdx.x;
  if (i < n) p[i] = 0;
}

// ---------------- transpose + f32->bf16 convert ----------------
// src: [E][R][C] f32 ; dst: [E][C][R] bf16. grid (C/32, R/32, E), block 256.
__global__ __launch_bounds__(256) void tcvt(const float* __restrict__ src,
                                            u16* __restrict__ dst, int R, int C) {
  __shared__ u16 tile[32][33];
  size_t off = (size_t)blockIdx.z * R * C;
  int cb = blockIdx.x * 32, rb = blockIdx.y * 32;
  int tx = threadIdx.x & 31, ty = threadIdx.x >> 5;
#pragma unroll
  for (int i = 0; i < 4; i++)
    tile[ty + i * 8][tx] = f2bf(src[off + (size_t)(rb + ty + i * 8) * C + cb + tx]);
  __syncthreads();
#pragma unroll
  for (int i = 0; i < 4; i++)
    dst[off + (size_t)(cb + ty + i * 8) * R + rb + tx] = tile[tx][ty + i * 8];
}

// ---------------- gating (+ X -> bf16) ----------------
// grid 2048, block 256 (4 waves, 1 token/wave)
__global__ __launch_bounds__(256) void gating(
    const float* __restrict__ X, const float* __restrict__ TP,
    const float* __restrict__ Wg, const float* __restrict__ bg,
    const float* __restrict__ Wt, const float* __restrict__ bgt,
    const float* __restrict__ alphaP, u16* __restrict__ Xb, int* meta) {
  __shared__ float WgT[E_EXP * D_DIM];   // [e][d] 32KB
  __shared__ float WtT[E_EXP * DT_DIM];  // 8KB
  int tid = threadIdx.x;
  for (int i = tid; i < E_EXP * D_DIM; i += 256) { int d = i >> 3, e = i & 7; WgT[e * D_DIM + d] = Wg[i]; }
  for (int i = tid; i < E_EXP * DT_DIM; i += 256) { int d = i >> 3, e = i & 7; WtT[e * DT_DIM + d] = Wt[i]; }
  __syncthreads();
  int lane = tid & 63, wid = tid >> 6;
  int t = blockIdx.x * 4 + wid;
  int b = t >> 11;  // S=2048
  const float* xrow = X + (size_t)t * D_DIM;
  float acc[8] = {0, 0, 0, 0, 0, 0, 0, 0};
#pragma unroll 4
  for (int i = 0; i < 16; i++) {
    int d = lane + i * 64;
    float x = xrow[d];
    Xb[(size_t)t * D_DIM + d] = f2bf(x);
#pragma unroll
    for (int e = 0; e < 8; e++) acc[e] += x * WgT[e * D_DIM + d];
  }
  const float* trow = TP + (size_t)b * DT_DIM;
  float tac[8] = {0, 0, 0, 0, 0, 0, 0, 0};
#pragma unroll
  for (int i = 0; i < 4; i++) {
    int d = lane + i * 64;
    float x = trow[d];
#pragma unroll
    for (int e = 0; e < 8; e++) tac[e] += x * WtT[e * DT_DIM + d];
  }
  for (int off = 32; off > 0; off >>= 1) {
#pragma unroll
    for (int e = 0; e < 8; e++) {
      acc[e] += __shfl_xor(acc[e], off);
      tac[e] += __shfl_xor(tac[e], off);
    }
  }
  if (lane == 0) {
    float alpha = alphaP[0];
    float gl[8];
#pragma unroll
    for (int e = 0; e < 8; e++)
      gl[e] = (1.f - alpha) * (acc[e] + bg[e]) + alpha * (tac[e] + bgt[e]);
    int e1 = 0;
#pragma unroll
    for (int e = 1; e < 8; e++) if (gl[e] > gl[e1]) e1 = e;
    int es = (e1 == 0) ? 1 : 0;
#pragma unroll
    for (int e = 0; e < 8; e++) if (e != e1 && gl[e] > gl[es]) es = e;
    float mx = gl[0];
#pragma unroll
    for (int e = 1; e < 8; e++) mx = fmaxf(mx, gl[e]);
    float pe[8], se = 0.f;
#pragma unroll
    for (int e = 0; e < 8; e++) { pe[e] = __expf(gl[e] - mx); se += pe[e]; }
    float inv = 1.f / se;
    float* sprob = (float*)meta + MO_SPROB / 4;
    int* counts = meta + MO_COUNTS / 4;
#pragma unroll
    for (int e = 0; e < 8; e++) atomicAdd(&sprob[e], pe[e] * inv);
    atomicAdd(&counts[e1], 1);
    atomicAdd(&counts[es], 1);
    float w1 = 1.f / (1.f + __expf(gl[es] - gl[e1]));
    meta[MO_ROUTEE / 4 + 2 * t] = e1;
    meta[MO_ROUTEE / 4 + 2 * t + 1] = es;
    ((float*)meta)[MO_ROUTEW / 4 + 2 * t] = w1;
    ((float*)meta)[MO_ROUTEW / 4 + 2 * t + 1] = 1.f - w1;
  }
}

// ---------------- plan: bases, tile map, l_aux ----------------
__global__ void plan(int* meta, float* out) {
  if (threadIdx.x != 0 || blockIdx.x != 0) return;
  int* counts = meta + MO_COUNTS / 4;
  int* pb = meta + MO_PB / 4;
  int* tileE = meta + MO_TILEE / 4;
  int* tileRB = meta + MO_TILERB / 4;
  float* sprob = (float*)meta + MO_SPROB / 4;
  int base = 0, nt = 0;
  float la = 0.f;
  for (int e = 0; e < 8; e++) {
    int n = counts[e];
    pb[e] = base;
    int ntl = (n + 127) >> 7;
    for (int i = 0; i < ntl; i++) { tileE[nt] = e; tileRB[nt] = base + (i << 7); nt++; }
    base += ntl << 7;
    la += (sprob[e] * (1.f / 8192.f)) * ((float)n * (1.f / 8192.f));
  }
  pb[8] = base;
  meta[MO_NT / 4] = nt;
  out[T_TOK * D_DIM] = la;  // l_aux
}

// ---------------- fill slot lists ----------------
__global__ __launch_bounds__(256) void fillk(int* meta) {
  int t = blockIdx.x * 256 + threadIdx.x;
  int* pb = meta + MO_PB / 4;
  int* fl = meta + MO_FILL / 4;
  int* ptok = meta + MO_PTOK / 4;
  int* ts = meta + MO_TSLOT / 4;
#pragma unroll
  for (int k = 0; k < 2; k++) {
    int e = meta[MO_ROUTEE / 4 + 2 * t + k];
    int pos = atomicAdd(&fl[e], 1);
    int slot = pb[e] + pos;
    ptok[slot] = t;
    ts[2 * t + k] = slot;
  }
}

// ---------------- GEMM1: h = silu(X[tok] @ W1[e] + b1[e]) ----------------
// grid (136, 32), block 256 (4 waves, 64x64 per wave). BT layout [F][D].
__global__ __launch_bounds__(256) void gemm1(
    const u16* __restrict__ Xb, const u16* __restrict__ W1T,
    const float* __restrict__ b1, u16* __restrict__ H, const int* __restrict__ meta) {
  int nt = meta[MO_NT / 4];
  int bt = blockIdx.x;
  if (bt >= nt) return;
  int e = meta[MO_TILEE / 4 + bt];
  int rb = meta[MO_TILERB / 4 + bt];
  int cb = blockIdx.y * 128;
  const int* ptok = meta + MO_PTOK / 4;

  __shared__ short sA[128 * 32];
  __shared__ short sB[128 * 32];
  int tid = threadIdx.x, lane = tid & 63, wid = tid >> 6;
  int wr = wid >> 1, wc = wid & 1;
  int r0 = tid >> 2, c0 = (tid & 3) << 3;
  int tok0 = ptok[rb + r0];
  int tok1 = ptok[rb + r0 + 64];
  const u16* gA0 = Xb + (size_t)tok0 * D_DIM + c0;
  const u16* gA1 = Xb + (size_t)tok1 * D_DIM + c0;
  const u16* gB0 = W1T + ((size_t)e * F_DIM + cb + r0) * D_DIM + c0;
  const u16* gB1 = gB0 + (size_t)64 * D_DIM;
  char* lA = (char*)sA + wid * 1024;
  char* lB = (char*)sB + wid * 1024;

  f32x4 acc[4][4] = {};
  for (int k0 = 0; k0 < D_DIM; k0 += 32) {
    __syncthreads();
    gload16(gA0 + k0, lA);
    gload16(gA1 + k0, lA + 4096);
    gload16(gB0 + k0, lB);
    gload16(gB1 + k0, lB + 4096);
    __syncthreads();
    bf16x8 af[4], bfr[4];
    int ra = wr * 64 + (lane & 15), kb = (lane >> 4) << 3;
#pragma unroll
    for (int m = 0; m < 4; m++)
      af[m] = *(const bf16x8*)((const char*)sA + ((ra + m * 16) * 32 + kb) * 2);
    int rn = wc * 64 + (lane & 15);
#pragma unroll
    for (int n = 0; n < 4; n++)
      bfr[n] = *(const bf16x8*)((const char*)sB + ((rn + n * 16) * 32 + kb) * 2);
#pragma unroll
    for (int m = 0; m < 4; m++)
#pragma unroll
      for (int n = 0; n < 4; n++)
        acc[m][n] = __builtin_amdgcn_mfma_f32_16x16x32_bf16(af[m], bfr[n], acc[m][n], 0, 0, 0);
  }
  int rbase = wr * 64 + ((lane >> 4) << 2);
  int cbase = cb + wc * 64 + (lane & 15);
#pragma unroll
  for (int m = 0; m < 4; m++)
#pragma unroll
    for (int n = 0; n < 4; n++) {
      int f = cbase + n * 16;
      float bias = b1[e * F_DIM + f];
#pragma unroll
      for (int r = 0; r < 4; r++) {
        int p = rb + rbase + m * 16 + r;
        float v = acc[m][n][r] + bias;
        float s = v * (1.0f / (1.0f + __expf(-v)));
        H[(size_t)p * F_DIM + f] = f2bf(s);
      }
    }
}

// ---------------- GEMM2: Y = h @ W2[e] + b2[e] ----------------
// grid (136, 8). BT layout W2T [D][F].
__global__ __launch_bounds__(256) void gemm2(
    const u16* __restrict__ H, const u16* __restrict__ W2T,
    const float* __restrict__ b2, u16* __restrict__ Y, const int* __restrict__ meta) {
  int nt = meta[MO_NT / 4];
  int bt = blockIdx.x;
  if (bt >= nt) return;
  int e = meta[MO_TILEE / 4 + bt];
  int rb = meta[MO_TILERB / 4 + bt];
  int cb = blockIdx.y * 128;
  __shared__ short sA[128 * 32];
  __shared__ short sB[128 * 32];
  int tid = threadIdx.x, lane = tid & 63, wid = tid >> 6;
  int wr = wid >> 1, wc = wid & 1;
  int r0 = tid >> 2, c0 = (tid & 3) << 3;
  const u16* gA0 = H + (size_t)(rb + r0) * F_DIM + c0;
  const u16* gA1 = gA0 + (size_t)64 * F_DIM;
  const u16* gB0 = W2T + ((size_t)e * D_DIM + cb + r0) * F_DIM + c0;
  const u16* gB1 = gB0 + (size_t)64 * F_DIM;
  char* lA = (char*)sA + wid * 1024;
  char* lB = (char*)sB + wid * 1024;

  f32x4 acc[4][4] = {};
  for (int k0 = 0; k0 < F_DIM; k0 += 32) {
    __syncthreads();
    gload16(gA0 + k0, lA);
    gload16(gA1 + k0, lA + 4096);
    gload16(gB0 + k0, lB);
    gload16(gB1 + k0, lB + 4096);
    __syncthreads();
    bf16x8 af[4], bfr[4];
    int ra = wr * 64 + (lane & 15), kb = (lane >> 4) << 3;
#pragma unroll
    for (int m = 0; m < 4; m++)
      af[m] = *(const bf16x8*)((const char*)sA + ((ra + m * 16) * 32 + kb) * 2);
    int rn = wc * 64 + (lane & 15);
#pragma unroll
    for (int n = 0; n < 4; n++)
      bfr[n] = *(const bf16x8*)((const char*)sB + ((rn + n * 16) * 32 + kb) * 2);
#pragma unroll
    for (int m = 0; m < 4; m++)
#pragma unroll
      for (int n = 0; n < 4; n++)
        acc[m][n] = __builtin_amdgcn_mfma_f32_16x16x32_bf16(af[m], bfr[n], acc[m][n], 0, 0, 0);
  }
  int rbase = wr * 64 + ((lane >> 4) << 2);
  int cbase = cb + wc * 64 + (lane & 15);
#pragma unroll
  for (int m = 0; m < 4; m++)
#pragma unroll
    for (int n = 0; n < 4; n++) {
      int d = cbase + n * 16;
      float bias = b2[e * D_DIM + d];
#pragma unroll
      for (int r = 0; r < 4; r++) {
        int p = rb + rbase + m * 16 + r;
        Y[(size_t)p * D_DIM + d] = f2bf(acc[m][n][r] + bias);
      }
    }
}

// ---------------- combine: out[t] = w1*Y[s1] + w2*Y[s2] ----------------
__global__ __launch_bounds__(256) void combine(const u16* __restrict__ Y,
                                               const int* __restrict__ meta,
                                               float* __restrict__ out) {
  int t = blockIdx.x;
  const int* ts = meta + MO_TSLOT / 4;
  const float* rw = (const float*)meta + MO_ROUTEW / 4;
  int s1 = ts[2 * t], s2 = ts[2 * t + 1];
  float w1 = rw[2 * t], w2 = rw[2 * t + 1];
  int d0 = threadIdx.x * 4;
  ushort4 a = *(const ushort4*)(Y + (size_t)s1 * D_DIM + d0);
  ushort4 b = *(const ushort4*)(Y + (size_t)s2 * D_DIM + d0);
  float4 v;
  v.x = w1 * bf2f(a.x) + w2 * bf2f(b.x);
  v.y = w1 * bf2f(a.y) + w2 * bf2f(b.y);
  v.z = w1 * bf2f(a.z) + w2 * bf2f(b.z);
  v.w = w1 * bf2f(a.w) + w2 * bf2f(b.w);
  *(float4*)(out + (size_t)t * D_DIM + d0) = v;
}

// ---------------- launch ----------------
extern "C" void kernel_launch(void* const* d_in, const int* in_sizes, int n_in,
                              void* d_out, int out_size, void* d_ws, size_t ws_size,
                              hipStream_t stream) {
  (void)in_sizes; (void)n_in; (void)out_size; (void)ws_size;
  const float* X    = (const float*)d_in[0];
  const float* TP   = (const float*)d_in[1];
  const float* Wg   = (const float*)d_in[2];
  const float* bg   = (const float*)d_in[3];
  const float* Wt   = (const float*)d_in[4];
  const float* bgt  = (const float*)d_in[5];
  const float* alp  = (const float*)d_in[6];
  const float* W1   = (const float*)d_in[7];
  const float* b1   = (const float*)d_in[8];
  const float* W2   = (const float*)d_in[9];
  const float* b2   = (const float*)d_in[10];
  float* out = (float*)d_out;
  char* ws = (char*)d_ws;
  u16* Xb = (u16*)(ws + A_XB);
  u16* WT = (u16*)(ws + A_WT);
  u16* H  = (u16*)(ws + A_H);
  u16* Y  = (u16*)(ws + A_Y);
  int* meta = (int*)(ws + A_META);

  zerok<<<(META_INTS + 255) / 256, 256, 0, stream>>>(meta, META_INTS);
  tcvt<<<dim3(F_DIM / 32, D_DIM / 32, E_EXP), 256, 0, stream>>>(W1, WT, D_DIM, F_DIM); // W1T [F][D]
  gating<<<T_TOK / 4, 256, 0, stream>>>(X, TP, Wg, bg, Wt, bgt, alp, Xb, meta);
  plan<<<1, 64, 0, stream>>>(meta, out);
  fillk<<<T_TOK / 256, 256, 0, stream>>>(meta);
  gemm1<<<dim3(136, F_DIM / 128), 256, 0, stream>>>(Xb, WT, b1, H, meta);
  tcvt<<<dim3(D_DIM / 32, F_DIM / 32, E_EXP), 256, 0, stream>>>(W2, WT, F_DIM, D_DIM); // W2T [D][F]
  gemm2<<<dim3(136, D_DIM / 128), 256, 0, stream>>>(H, WT, b2, Y, meta);
  combine<<<T_TOK, 256, 0, stream>>>(Y, meta, out);
}

// Round 2
// 636.750 us; speedup vs baseline: 2.3225x; 2.3225x over previous
//
#include <hip/hip_runtime.h>

// ---------------- problem constants ----------------
#define T_TOK 8192      // B*S tokens
#define D_DIM 1024
#define F_DIM 4096
#define E_EXP 8
#define DT_DIM 256
#define GBLK 256        // gating blocks (32 tokens each)

// ---------------- workspace layout (bytes) ----------------
#define A_XB   0u                    // bf16 X   [8192][1024]   16,777,216
#define A_WT   16777216u             // bf16 W1T then W2T       67,108,864
#define A_H    83886080u             // bf16 h   [17408][4096] 142,606,336
#define A_Y    226492416u            // bf16 Y   [17408][1024]  35,651,584
#define A_META 262144000u
// meta byte offsets
#define MO_FILL   0        // 8 ints (atomic fill cursors)
#define MO_PB     64       // 9 ints (expert segment bases)
#define MO_NT     128      // 1 int
#define MO_PARTP  256      // f32[256][8] per-block prob partials (8KB)
#define MO_PARTC  8448     // int[256][8] per-block count partials (8KB)
#define MO_TILEE  16640    // int[160]
#define MO_TILERB 17664    // int[160]
#define MO_ROUTEE 18688    // int[16384]
#define MO_ROUTEW 84224    // f32[16384]
#define MO_TSLOT  149760   // int[16384]
#define MO_PTOK   215296   // int[17408]
#define META_BYTES 284928
#define META_INTS  (META_BYTES/4)

using bf16x8 = __attribute__((ext_vector_type(8))) short;
using f32x4  = __attribute__((ext_vector_type(4))) float;
typedef unsigned short u16;

__device__ __forceinline__ u16 f2bf(float f) {
  union { float f; unsigned u; } v; v.f = f;
  unsigned r = v.u + 0x7FFFu + ((v.u >> 16) & 1u);   // RNE
  return (u16)(r >> 16);
}
__device__ __forceinline__ float bf2f(u16 h) {
  union { unsigned u; float f; } v; v.u = ((unsigned)h) << 16; return v.f;
}
__device__ __forceinline__ void gload16(const void* gsrc, void* ldst) {
  __builtin_amdgcn_global_load_lds(
      (const __attribute__((address_space(1))) void*)gsrc,
      (__attribute__((address_space(3))) void*)ldst, 16, 0, 0);
}

// ---------------- zero meta ----------------
__global__ void zerok(int* p, int n) {
  int i = blockIdx.x * 256 + threadIdx.x;
  if (i < n) p[i] = 0;
}

// ---------------- transpose + f32->bf16 convert ----------------
__global__ __launch_bounds__(256) void tcvt(const float* __restrict__ src,
                                            u16* __restrict__ dst, int R, int C) {
  __shared__ u16 tile[32][33];
  size_t off = (size_t)blockIdx.z * R * C;
  int cb = blockIdx.x * 32, rb = blockIdx.y * 32;
  int tx = threadIdx.x & 31, ty = threadIdx.x >> 5;
#pragma unroll
  for (int i = 0; i < 4; i++)
    tile[ty + i * 8][tx] = f2bf(src[off + (size_t)(rb + ty + i * 8) * C + cb + tx]);
  __syncthreads();
#pragma unroll
  for (int i = 0; i < 4; i++)
    dst[off + (size_t)(cb + ty + i * 8) * R + rb + tx] = tile[tx][ty + i * 8];
}

// ---------------- gating (+ X -> bf16), NO atomics ----------------
// grid GBLK=256, block 256 (4 waves); 32 tokens/block, 8 tokens/wave.
__global__ __launch_bounds__(256) void gating(
    const float* __restrict__ X, const float* __restrict__ TP,
    const float* __restrict__ Wg, const float* __restrict__ bg,
    const float* __restrict__ Wt, const float* __restrict__ bgt,
    const float* __restrict__ alphaP, u16* __restrict__ Xb, int* meta) {
  __shared__ float WgT[E_EXP * D_DIM];   // [e][d] 32KB
  __shared__ float WtT[E_EXP * DT_DIM];  // 8KB
  __shared__ float wsP[4][8];
  __shared__ int   wsC[4][8];
  int tid = threadIdx.x;
  for (int i = tid; i < E_EXP * D_DIM; i += 256) { int d = i >> 3, e = i & 7; WgT[e * D_DIM + d] = Wg[i]; }
  for (int i = tid; i < E_EXP * DT_DIM; i += 256) { int d = i >> 3, e = i & 7; WtT[e * DT_DIM + d] = Wt[i]; }
  __syncthreads();
  int lane = tid & 63, wid = tid >> 6;
  int tb = blockIdx.x * 32;
  int b = tb >> 11;  // S=2048, 32 | 2048 -> block spans one batch row
  float alpha = alphaP[0];

  // task logits (redundant per wave, cheap)
  float tac[8] = {};
#pragma unroll
  for (int i = 0; i < 4; i++) {
    int d = lane + i * 64;
    float x = TP[b * DT_DIM + d];
#pragma unroll
    for (int e = 0; e < 8; e++) tac[e] += x * WtT[e * DT_DIM + d];
  }
  for (int off = 32; off > 0; off >>= 1)
#pragma unroll
    for (int e = 0; e < 8; e++) tac[e] += __shfl_xor(tac[e], off);
  float tl[8];
#pragma unroll
  for (int e = 0; e < 8; e++) tl[e] = alpha * (tac[e] + bgt[e]);

  float psum[8] = {};
  int   cnt[8] = {};
  for (int i = 0; i < 8; i++) {
    int t = tb + wid * 8 + i;
    const float* xr = X + (size_t)t * D_DIM;
    float acc[8] = {};
    u16 xb[16];
#pragma unroll 4
    for (int j = 0; j < 16; j++) {
      int d = lane + j * 64;
      float x = xr[d];
      xb[j] = f2bf(x);
#pragma unroll
      for (int e = 0; e < 8; e++) acc[e] += x * WgT[e * D_DIM + d];
    }
#pragma unroll
    for (int j = 0; j < 16; j++) Xb[(size_t)t * D_DIM + lane + j * 64] = xb[j];
    for (int off = 32; off > 0; off >>= 1)
#pragma unroll
      for (int e = 0; e < 8; e++) acc[e] += __shfl_xor(acc[e], off);
    // all lanes hold full logits now (uniform)
    float gl[8];
#pragma unroll
    for (int e = 0; e < 8; e++) gl[e] = (1.f - alpha) * (acc[e] + bg[e]) + tl[e];
    int e1 = 0;
#pragma unroll
    for (int e = 1; e < 8; e++) if (gl[e] > gl[e1]) e1 = e;
    int es = (e1 == 0) ? 1 : 0;
#pragma unroll
    for (int e = 0; e < 8; e++) if (e != e1 && gl[e] > gl[es]) es = e;
    float mx = gl[0];
#pragma unroll
    for (int e = 1; e < 8; e++) mx = fmaxf(mx, gl[e]);
    float pe[8], se = 0.f;
#pragma unroll
    for (int e = 0; e < 8; e++) { pe[e] = __expf(gl[e] - mx); se += pe[e]; }
    float inv = 1.f / se;
    if (lane == 0) {
#pragma unroll
      for (int e = 0; e < 8; e++) psum[e] += pe[e] * inv;
      cnt[e1]++; cnt[es]++;
      float w1 = 1.f / (1.f + __expf(gl[es] - gl[e1]));
      meta[MO_ROUTEE / 4 + 2 * t] = e1;
      meta[MO_ROUTEE / 4 + 2 * t + 1] = es;
      ((float*)meta)[MO_ROUTEW / 4 + 2 * t] = w1;
      ((float*)meta)[MO_ROUTEW / 4 + 2 * t + 1] = 1.f - w1;
    }
  }
  if (lane == 0) {
#pragma unroll
    for (int e = 0; e < 8; e++) { wsP[wid][e] = psum[e]; wsC[wid][e] = cnt[e]; }
  }
  __syncthreads();
  if (tid < 8) {
    float p = wsP[0][tid] + wsP[1][tid] + wsP[2][tid] + wsP[3][tid];
    int   c = wsC[0][tid] + wsC[1][tid] + wsC[2][tid] + wsC[3][tid];
    ((float*)meta)[MO_PARTP / 4 + blockIdx.x * 8 + tid] = p;
    meta[MO_PARTC / 4 + blockIdx.x * 8 + tid] = c;
  }
}

// ---------------- plan: deterministic reduce + bases + tile map + l_aux ----------------
__global__ void plan(int* meta, float* out) {
  __shared__ float sp[8];
  __shared__ int   sc[8];
  int tid = threadIdx.x;
  if (blockIdx.x != 0) return;
  if (tid < 8) {
    const float* pp = (const float*)meta + MO_PARTP / 4;
    const int*   pc = meta + MO_PARTC / 4;
    float p = 0.f; int c = 0;
    for (int b = 0; b < GBLK; b++) { p += pp[b * 8 + tid]; c += pc[b * 8 + tid]; }
    sp[tid] = p; sc[tid] = c;
  }
  __syncthreads();
  if (tid == 0) {
    int* pb = meta + MO_PB / 4;
    int* tileE = meta + MO_TILEE / 4;
    int* tileRB = meta + MO_TILERB / 4;
    int base = 0, nt = 0;
    float la = 0.f;
    for (int e = 0; e < 8; e++) {
      int n = sc[e];
      pb[e] = base;
      int ntl = (n + 127) >> 7;
      for (int i = 0; i < ntl; i++) { tileE[nt] = e; tileRB[nt] = base + (i << 7); nt++; }
      base += ntl << 7;
      la += (sp[e] * (1.f / 8192.f)) * ((float)n * (1.f / 8192.f));
    }
    pb[8] = base;
    meta[MO_NT / 4] = nt;
    out[T_TOK * D_DIM] = la;  // l_aux
  }
}

// ---------------- fill slot lists (wave-aggregated atomics) ----------------
__global__ __launch_bounds__(256) void fillk(int* meta) {
  int t = blockIdx.x * 256 + threadIdx.x;
  int lane = threadIdx.x & 63;
  int* pb = meta + MO_PB / 4;
  int* fl = meta + MO_FILL / 4;
  int* ptok = meta + MO_PTOK / 4;
  int* ts = meta + MO_TSLOT / 4;
  unsigned long long lmask = (lane == 63) ? ~0ull >> 1 : ((1ull << (lane + 1)) - 1) >> 1;
  lmask = (1ull << lane) - 1;  // lanes below
#pragma unroll
  for (int k = 0; k < 2; k++) {
    int e = meta[MO_ROUTEE / 4 + 2 * t + k];
    int slot = 0;
    for (int ee = 0; ee < 8; ee++) {
      unsigned long long mask = __ballot(e == ee);
      if (e == ee) {
        int low = __ffsll((long long)mask) - 1;
        int pre = __popcll(mask & lmask);
        int base = 0;
        if (lane == low) base = atomicAdd(&fl[ee], __popcll(mask));
        base = __shfl(base, low);
        slot = pb[ee] + base + pre;
      }
    }
    ptok[slot] = t;
    ts[2 * t + k] = slot;
  }
}

// ---------------- GEMM1: h = silu(X[tok] @ W1[e] + b1[e]) ----------------
__global__ __launch_bounds__(256) void gemm1(
    const u16* __restrict__ Xb, const u16* __restrict__ W1T,
    const float* __restrict__ b1, u16* __restrict__ H, const int* __restrict__ meta) {
  int nt = meta[MO_NT / 4];
  int bt = blockIdx.x;
  if (bt >= nt) return;
  int e = meta[MO_TILEE / 4 + bt];
  int rb = meta[MO_TILERB / 4 + bt];
  int cb = blockIdx.y * 128;
  const int* ptok = meta + MO_PTOK / 4;

  __shared__ short sA[128 * 32];
  __shared__ short sB[128 * 32];
  int tid = threadIdx.x, lane = tid & 63, wid = tid >> 6;
  int wr = wid >> 1, wc = wid & 1;
  int r0 = tid >> 2, c0 = (tid & 3) << 3;
  int tok0 = ptok[rb + r0];
  int tok1 = ptok[rb + r0 + 64];
  const u16* gA0 = Xb + (size_t)tok0 * D_DIM + c0;
  const u16* gA1 = Xb + (size_t)tok1 * D_DIM + c0;
  const u16* gB0 = W1T + ((size_t)e * F_DIM + cb + r0) * D_DIM + c0;
  const u16* gB1 = gB0 + (size_t)64 * D_DIM;
  char* lA = (char*)sA + wid * 1024;
  char* lB = (char*)sB + wid * 1024;

  f32x4 acc[4][4] = {};
  for (int k0 = 0; k0 < D_DIM; k0 += 32) {
    __syncthreads();
    gload16(gA0 + k0, lA);
    gload16(gA1 + k0, lA + 4096);
    gload16(gB0 + k0, lB);
    gload16(gB1 + k0, lB + 4096);
    __syncthreads();
    bf16x8 af[4], bfr[4];
    int ra = wr * 64 + (lane & 15), kb = (lane >> 4) << 3;
#pragma unroll
    for (int m = 0; m < 4; m++)
      af[m] = *(const bf16x8*)((const char*)sA + ((ra + m * 16) * 32 + kb) * 2);
    int rn = wc * 64 + (lane & 15);
#pragma unroll
    for (int n = 0; n < 4; n++)
      bfr[n] = *(const bf16x8*)((const char*)sB + ((rn + n * 16) * 32 + kb) * 2);
#pragma unroll
    for (int m = 0; m < 4; m++)
#pragma unroll
      for (int n = 0; n < 4; n++)
        acc[m][n] = __builtin_amdgcn_mfma_f32_16x16x32_bf16(af[m], bfr[n], acc[m][n], 0, 0, 0);
  }
  int rbase = wr * 64 + ((lane >> 4) << 2);
  int cbase = cb + wc * 64 + (lane & 15);
#pragma unroll
  for (int m = 0; m < 4; m++)
#pragma unroll
    for (int n = 0; n < 4; n++) {
      int f = cbase + n * 16;
      float bias = b1[e * F_DIM + f];
#pragma unroll
      for (int r = 0; r < 4; r++) {
        int p = rb + rbase + m * 16 + r;
        float v = acc[m][n][r] + bias;
        float s = v * (1.0f / (1.0f + __expf(-v)));
        H[(size_t)p * F_DIM + f] = f2bf(s);
      }
    }
}

// ---------------- GEMM2: Y = h @ W2[e] + b2[e] ----------------
__global__ __launch_bounds__(256) void gemm2(
    const u16* __restrict__ H, const u16* __restrict__ W2T,
    const float* __restrict__ b2, u16* __restrict__ Y, const int* __restrict__ meta) {
  int nt = meta[MO_NT / 4];
  int bt = blockIdx.x;
  if (bt >= nt) return;
  int e = meta[MO_TILEE / 4 + bt];
  int rb = meta[MO_TILERB / 4 + bt];
  int cb = blockIdx.y * 128;
  __shared__ short sA[128 * 32];
  __shared__ short sB[128 * 32];
  int tid = threadIdx.x, lane = tid & 63, wid = tid >> 6;
  int wr = wid >> 1, wc = wid & 1;
  int r0 = tid >> 2, c0 = (tid & 3) << 3;
  const u16* gA0 = H + (size_t)(rb + r0) * F_DIM + c0;
  const u16* gA1 = gA0 + (size_t)64 * F_DIM;
  const u16* gB0 = W2T + ((size_t)e * D_DIM + cb + r0) * F_DIM + c0;
  const u16* gB1 = gB0 + (size_t)64 * F_DIM;
  char* lA = (char*)sA + wid * 1024;
  char* lB = (char*)sB + wid * 1024;

  f32x4 acc[4][4] = {};
  for (int k0 = 0; k0 < F_DIM; k0 += 32) {
    __syncthreads();
    gload16(gA0 + k0, lA);
    gload16(gA1 + k0, lA + 4096);
    gload16(gB0 + k0, lB);
    gload16(gB1 + k0, lB + 4096);
    __syncthreads();
    bf16x8 af[4], bfr[4];
    int ra = wr * 64 + (lane & 15), kb = (lane >> 4) << 3;
#pragma unroll
    for (int m = 0; m < 4; m++)
      af[m] = *(const bf16x8*)((const char*)sA + ((ra + m * 16) * 32 + kb) * 2);
    int rn = wc * 64 + (lane & 15);
#pragma unroll
    for (int n = 0; n < 4; n++)
      bfr[n] = *(const bf16x8*)((const char*)sB + ((rn + n * 16) * 32 + kb) * 2);
#pragma unroll
    for (int m = 0; m < 4; m++)
#pragma unroll
      for (int n = 0; n < 4; n++)
        acc[m][n] = __builtin_amdgcn_mfma_f32_16x16x32_bf16(af[m], bfr[n], acc[m][n], 0, 0, 0);
  }
  int rbase = wr * 64 + ((lane >> 4) << 2);
  int cbase = cb + wc * 64 + (lane & 15);
#pragma unroll
  for (int m = 0; m < 4; m++)
#pragma unroll
    for (int n = 0; n < 4; n++) {
      int d = cbase + n * 16;
      float bias = b2[e * D_DIM + d];
#pragma unroll
      for (int r = 0; r < 4; r++) {
        int p = rb + rbase + m * 16 + r;
        Y[(size_t)p * D_DIM + d] = f2bf(acc[m][n][r] + bias);
      }
    }
}

// ---------------- combine: out[t] = w1*Y[s1] + w2*Y[s2] ----------------
__global__ __launch_bounds__(256) void combine(const u16* __restrict__ Y,
                                               const int* __restrict__ meta,
                                               float* __restrict__ out) {
  int t = blockIdx.x;
  const int* ts = meta + MO_TSLOT / 4;
  const float* rw = (const float*)meta + MO_ROUTEW / 4;
  int s1 = ts[2 * t], s2 = ts[2 * t + 1];
  float w1 = rw[2 * t], w2 = rw[2 * t + 1];
  int d0 = threadIdx.x * 4;
  ushort4 a = *(const ushort4*)(Y + (size_t)s1 * D_DIM + d0);
  ushort4 b = *(const ushort4*)(Y + (size_t)s2 * D_DIM + d0);
  float4 v;
  v.x = w1 * bf2f(a.x) + w2 * bf2f(b.x);
  v.y = w1 * bf2f(a.y) + w2 * bf2f(b.y);
  v.z = w1 * bf2f(a.z) + w2 * bf2f(b.z);
  v.w = w1 * bf2f(a.w) + w2 * bf2f(b.w);
  *(float4*)(out + (size_t)t * D_DIM + d0) = v;
}

// ---------------- launch ----------------
extern "C" void kernel_launch(void* const* d_in, const int* in_sizes, int n_in,
                              void* d_out, int out_size, void* d_ws, size_t ws_size,
                              hipStream_t stream) {
  (void)in_sizes; (void)n_in; (void)out_size; (void)ws_size;
  const float* X    = (const float*)d_in[0];
  const float* TP   = (const float*)d_in[1];
  const float* Wg   = (const float*)d_in[2];
  const float* bg   = (const float*)d_in[3];
  const float* Wt   = (const float*)d_in[4];
  const float* bgt  = (const float*)d_in[5];
  const float* alp  = (const float*)d_in[6];
  const float* W1   = (const float*)d_in[7];
  const float* b1   = (const float*)d_in[8];
  const float* W2   = (const float*)d_in[9];
  const float* b2   = (const float*)d_in[10];
  float* out = (float*)d_out;
  char* ws = (char*)d_ws;
  u16* Xb = (u16*)(ws + A_XB);
  u16* WT = (u16*)(ws + A_WT);
  u16* H  = (u16*)(ws + A_H);
  u16* Y  = (u16*)(ws + A_Y);
  int* meta = (int*)(ws + A_META);

  zerok<<<(META_INTS + 255) / 256, 256, 0, stream>>>(meta, META_INTS);
  tcvt<<<dim3(F_DIM / 32, D_DIM / 32, E_EXP), 256, 0, stream>>>(W1, WT, D_DIM, F_DIM); // W1T [F][D]
  gating<<<GBLK, 256, 0, stream>>>(X, TP, Wg, bg, Wt, bgt, alp, Xb, meta);
  plan<<<1, 64, 0, stream>>>(meta, out);
  fillk<<<T_TOK / 256, 256, 0, stream>>>(meta);
  gemm1<<<dim3(136, F_DIM / 128), 256, 0, stream>>>(Xb, WT, b1, H, meta);
  tcvt<<<dim3(D_DIM / 32, F_DIM / 32, E_EXP), 256, 0, stream>>>(W2, WT, F_DIM, D_DIM); // W2T [D][F]
  gemm2<<<dim3(136, D_DIM / 128), 256, 0, stream>>>(H, WT, b2, Y, meta);
  combine<<<T_TOK, 256, 0, stream>>>(Y, meta, out);
}